// Round 13
// baseline (606.918 us; speedup 1.0000x reference)
//
#include <hip/hip_runtime.h>

constexpr int N_NODES = 100000;
constexpr int N_EDGES = 1600000;
constexpr int N_CLUST = 25000;
constexpr int N_GRAPH = 64;
constexpr int NCLSN   = 10;

// bucket decomposition for the radix node-CSR build
constexpr int BKT1_SHIFT = 9;                       // node-dst buckets of 512 ids
constexpr int NBKT1 = (N_NODES + 511) / 512;        // 196
constexpr int EPB = 4096;                           // edges per block (count/scatter)
constexpr int NEB = (N_EDGES + EPB - 1) / EPB;      // 391
constexpr int SORT_CAP = 12288;                     // LDS staging cap (mean 8163, sd ~90)
constexpr int NZB = 16;                             // zero-fill blocks fused into count

// scan partitioning: 1024 elements per block, three concatenated segments
constexpr int SCAN_BPB = 1024;
constexpr int NB1 = (N_NODES + SCAN_BPB - 1) / SCAN_BPB;  // 98
constexpr int NB2 = (N_CLUST + SCAN_BPB - 1) / SCAN_BPB;  // 25
constexpr int NB3 = (N_CLUST + SCAN_BPB - 1) / SCAN_BPB;  // 25
constexpr int NBT = NB1 + NB2 + NB3;                      // 148

// fused-kernel grid splits
constexpr int G1  = (N_NODES + 63) / 64;            // gemm1 blocks (1563)
constexpr int FN  = (N_NODES + 255) / 256;          // fill_n blocks (391)
constexpr int C1  = N_NODES / 4;                    // conv1 blocks (25000)
constexpr int PS  = N_CLUST / 4;                    // psrc blocks (6250)
constexpr int CG  = N_CLUST / 4;                    // cluster_gather blocks
constexpr int PRE_SPLIT = 8;
constexpr int PP  = N_GRAPH * PRE_SPLIT;            // pre_pool blocks (512)
constexpr int G2  = (N_CLUST + 63) / 64;            // gemm2/3 blocks (391)
constexpr int POST_SPLIT = 4;

// ---- bf16 pack/unpack helpers (features stored as packed pairs in uint) ----
__device__ __forceinline__ float bf16lo(unsigned u){ return __uint_as_float(u << 16); }
__device__ __forceinline__ float bf16hi(unsigned u){ return __uint_as_float(u & 0xffff0000u); }
__device__ __forceinline__ unsigned bf16_rne(float f){
  unsigned u = __float_as_uint(f);
  return (u + 0x7fffu + ((u >> 16) & 1u)) >> 16;
}
__device__ __forceinline__ unsigned pack2(float lo, float hi){
  return bf16_rne(lo) | (bf16_rne(hi) << 16);
}

typedef short bf16x8 __attribute__((ext_vector_type(8)));
typedef float f32x4  __attribute__((ext_vector_type(4)));

__device__ __forceinline__ int bsearch_batch(const int* __restrict__ batch, int g){
  int lo = 0, hi = N_NODES;
  while (lo < hi){ int mid = (lo + hi) >> 1; if (batch[mid] < g) lo = mid + 1; else hi = mid; }
  return lo;
}

// ---------------------------------------------------------------------------
// node 1: per-block bucket histograms + workspace zeroing (fused)
// ---------------------------------------------------------------------------
__launch_bounds__(1024)
__global__ void count_kernel(const int* __restrict__ ei, int* __restrict__ bhist,
                             uint4* __restrict__ zbase, int zwords4){
  int t = threadIdx.x;
  if (blockIdx.x >= NEB){                      // zero-fill blocks
    int zb = blockIdx.x - NEB;
    for (int i = zb * 1024 + t; i < zwords4; i += NZB * 1024)
      zbase[i] = (uint4){0u, 0u, 0u, 0u};
    return;
  }
  __shared__ int h1c[NBKT1];
  for (int i = t; i < NBKT1; i += 1024) h1c[i] = 0;
  __syncthreads();
  int e0 = blockIdx.x * EPB;
  #pragma unroll
  for (int i = 0; i < EPB / 1024; ++i){
    int e = e0 + i * 1024 + t;
    if (e < N_EDGES) atomicAdd(&h1c[ei[N_EDGES + e] >> BKT1_SHIFT], 1);
  }
  __syncthreads();
  for (int i = t; i < NBKT1; i += 1024) bhist[blockIdx.x * NBKT1 + i] = h1c[i];
}

// node 2: column scan of the histogram matrix -> per-(block,bucket) offsets
__launch_bounds__(512)
__global__ void colscan(const int* __restrict__ bhist, int* __restrict__ boffs,
                        int* __restrict__ gcnt1){
  __shared__ int s[512];
  int i = blockIdx.x;                 // bucket
  int t = threadIdx.x;                // edge-block index
  int v = (t < NEB) ? bhist[t * NBKT1 + i] : 0;
  s[t] = v; __syncthreads();
  for (int o = 1; o < 512; o <<= 1){
    int a = (t >= o) ? s[t - o] : 0;
    __syncthreads(); s[t] += a; __syncthreads();
  }
  if (t < NEB) boffs[t * NBKT1 + i] = s[t] - v;   // exclusive within column
  if (t == 511) gcnt1[i] = s[511];
}

// in-block inclusive scan of gcnt1 into LDS s[256] (callers: scatter, sort)
__device__ __forceinline__ void scan_gcnt(const int* __restrict__ gcnt1, int* s, int t){
  if (t < 256) s[t] = (t < NBKT1) ? gcnt1[t] : 0;
  __syncthreads();
  for (int o = 1; o < 256; o <<= 1){
    int a = 0;
    if (t < 256 && t >= o) a = s[t - o];
    __syncthreads();
    if (t < 256) s[t] += a;
    __syncthreads();
  }
}

// node 3: single-pass scatter into pre-reserved runs (bases computed in-block)
__launch_bounds__(1024)
__global__ void scatter_kernel(const int* __restrict__ ei, const int* __restrict__ gcnt1,
                               const int* __restrict__ boffs, unsigned int* __restrict__ stage1){
  __shared__ int s[256];
  __shared__ int gb1[NBKT1];
  __shared__ int cur[NBKT1];
  int t = threadIdx.x, b = blockIdx.x;
  scan_gcnt(gcnt1, s, t);
  if (t < NBKT1){
    gb1[t] = (t ? s[t - 1] : 0) + boffs[b * NBKT1 + t];
    cur[t] = 0;
  }
  __syncthreads();
  int e0 = b * EPB;
  #pragma unroll
  for (int i = 0; i < EPB / 1024; ++i){
    int e = e0 + i * 1024 + t;
    if (e < N_EDGES){
      int src = ei[e], dst = ei[N_EDGES + e];
      int bk = dst >> BKT1_SHIFT;
      int r = atomicAdd(&cur[bk], 1);
      stage1[gb1[bk] + r] = ((unsigned)(dst & 511) << 17) | (unsigned)src;
    }
  }
}

// node 4: per-bucket LDS counting sort + degree writes + node_prep (fused)
__launch_bounds__(1024)
__global__ void bucket_sort(const unsigned int* __restrict__ stage, const int* __restrict__ gcnt1,
                            int* __restrict__ outpay, int* __restrict__ deg,
                            const int* __restrict__ cluster, int* __restrict__ cntn,
                            int* __restrict__ deg2){
  __shared__ int sg[256];
  __shared__ int cnt[512], off[512];
  __shared__ int sorted[SORT_CAP];
  __shared__ int baseSh;
  int b = blockIdx.x, t = threadIdx.x;
  scan_gcnt(gcnt1, sg, t);
  if (t == 0) baseSh = b ? sg[b - 1] : 0;
  if (t < 512) cnt[t] = 0;
  __syncthreads();
  int base = baseSh, n = gcnt1[b];
  for (int i = t; i < n; i += 1024) atomicAdd(&cnt[stage[base + i] >> 17], 1);
  __syncthreads();
  if (t < 512){
    int idx = b * 512 + t;
    if (idx < N_NODES) deg[idx] = cnt[t];
    off[t] = cnt[t];
  }
  __syncthreads();
  for (int s2 = 1; s2 < 512; s2 <<= 1){
    int v = 0;
    if (t < 512 && t >= s2) v = off[t - s2];
    __syncthreads();
    if (t < 512) off[t] += v;
    __syncthreads();
  }
  if (t < 512) off[t] -= cnt[t];       // exclusive cursors
  __syncthreads();
  if (n <= SORT_CAP){
    for (int i = t; i < n; i += 1024){
      unsigned w = stage[base + i];
      int r = atomicAdd(&off[w >> 17], 1);
      sorted[r] = (int)(w & 0x1FFFFu);
    }
    __syncthreads();
    for (int i = t; i < n; i += 1024) outpay[base + i] = sorted[i];
  } else {  // never expected; correct fallback
    for (int i = t; i < n; i += 1024){
      unsigned w = stage[base + i];
      int r = atomicAdd(&off[w >> 17], 1);
      outpay[base + r] = (int)(w & 0x1FFFFu);
    }
  }
  // node_prep tail: this block owns nodes [b*512, b*512+512)
  if (t < 512){
    int idx = b * 512 + t;
    if (idx < N_NODES){
      int c = cluster[idx];
      atomicAdd(&cntn[c], 1);
      atomicAdd(&deg2[c], cnt[t]);
    }
  }
}

// ---------------------------------------------------------------------------
// 3-segment exclusive scan (node 5: block sums; node 6: final w/ in-block bsum scan)
// ---------------------------------------------------------------------------
__device__ __forceinline__ void seg_select(int b, const int* deg1, const int* cntn,
                                           const int* deg2, const int*& src, int& n, int& base){
  if (b < NB1){ src = deg1; n = N_NODES; base = b * SCAN_BPB; }
  else if (b < NB1 + NB2){ src = cntn; n = N_CLUST; base = (b - NB1) * SCAN_BPB; }
  else { src = deg2; n = N_CLUST; base = (b - NB1 - NB2) * SCAN_BPB; }
}

__launch_bounds__(256)
__global__ void block_sums(const int* __restrict__ deg1, const int* __restrict__ cntn,
                           const int* __restrict__ deg2, int* __restrict__ bsum){
  int b = blockIdx.x;
  const int* src; int n, base;
  seg_select(b, deg1, cntn, deg2, src, n, base);
  int t = threadIdx.x;
  int i0 = base + t * 4;
  int s = 0;
  if (i0 + 3 < n){ int4 v = *(const int4*)&src[i0]; s = v.x + v.y + v.z + v.w; }
  else { for (int j = 0; j < 4; ++j){ int i = i0 + j; if (i < n) s += src[i]; } }
  __shared__ int sh[256];
  sh[t] = s; __syncthreads();
  for (int off = 128; off > 0; off >>= 1){
    if (t < off) sh[t] += sh[t + off];
    __syncthreads();
  }
  if (t == 0) bsum[b] = sh[0];
}

__launch_bounds__(256)
__global__ void scan_final(const int* __restrict__ deg1, const int* __restrict__ cntn,
                           const int* __restrict__ deg2, const int* __restrict__ bsum,
                           int* __restrict__ rowptr1, float* __restrict__ dis1,
                           int* __restrict__ rowptrn, int* __restrict__ curn,
                           int* __restrict__ rowptr2, float* __restrict__ dis2){
  int b = blockIdx.x;
  int t = threadIdx.x;
  // in-block segmented scan of bsum[NBT]
  __shared__ int sb[256];
  int bv = (t < NBT) ? bsum[t] : 0;
  sb[t] = bv; __syncthreads();
  int seg = (t < NB1) ? 0 : (t < NB1 + NB2 ? 1 : 2);
  for (int off = 1; off < 256; off <<= 1){
    int add = 0;
    if (t >= off){
      int u = t - off;
      int useg = (u < NB1) ? 0 : (u < NB1 + NB2 ? 1 : 2);
      if (useg == seg) add = sb[u];
    }
    __syncthreads();
    sb[t] += add;
    __syncthreads();
  }
  if (b == 0){
    if (t == NB1 - 1)       rowptr1[N_NODES] = sb[t];
    if (t == NB1 + NB2 - 1) rowptrn[N_CLUST] = sb[t];
    if (t == NBT - 1)       rowptr2[N_CLUST] = sb[t];
  }
  int boff_b = sb[b] - bsum[b];       // exclusive block offset for this block
  __syncthreads();

  const int* src; int n, base;
  seg_select(b, deg1, cntn, deg2, src, n, base);
  int* rp; int* cur; float* dis;
  if (b < NB1){ rp = rowptr1; cur = nullptr; dis = dis1; }
  else if (b < NB1 + NB2){ rp = rowptrn; cur = curn; dis = nullptr; }
  else { rp = rowptr2; cur = nullptr; dis = dis2; }
  int i0 = base + t * 4;
  int v[4]; int s = 0;
  #pragma unroll
  for (int j = 0; j < 4; ++j){ int i = i0 + j; v[j] = (i < n) ? src[i] : 0; s += v[j]; }
  __shared__ int sh[256];
  sh[t] = s; __syncthreads();
  for (int off = 1; off < 256; off <<= 1){
    int add = (t >= off) ? sh[t - off] : 0;
    __syncthreads();
    sh[t] += add;
    __syncthreads();
  }
  int run = sh[t] - s + boff_b;
  #pragma unroll
  for (int j = 0; j < 4; ++j){
    int i = i0 + j;
    if (i < n){
      rp[i] = run;
      if (cur) cur[i] = run;
      if (dis) dis[i] = rsqrtf((float)v[j] + 1.0f);
      run += v[j];
    }
  }
}

// ---------------------------------------------------------------------------
// MFMA GEMM body (device fn): C[M,128]=(A@B)*scale[row], bf16 packed out
// ---------------------------------------------------------------------------
template<bool A_BF16>
__device__ void gemm_body(int bm, const void* __restrict__ Aptr, const float* __restrict__ B,
                          const float* __restrict__ scale, unsigned* __restrict__ Cmat, int M){
  __shared__ __align__(16) unsigned Blds[128 * 68];
  __shared__ __align__(16) unsigned Alds[64 * 68];
  const int t = threadIdx.x;
  const int row0 = bm * 64;

  #pragma unroll
  for (int i = 0; i < 8; ++i){
    int task = t + i * 256;
    int kp = task >> 5, nq = task & 31;
    float4 b0 = *(const float4*)&B[(2 * kp) * 128 + nq * 4];
    float4 b1 = *(const float4*)&B[(2 * kp + 1) * 128 + nq * 4];
    Blds[(nq * 4 + 0) * 68 + kp] = pack2(b0.x, b1.x);
    Blds[(nq * 4 + 1) * 68 + kp] = pack2(b0.y, b1.y);
    Blds[(nq * 4 + 2) * 68 + kp] = pack2(b0.z, b1.z);
    Blds[(nq * 4 + 3) * 68 + kp] = pack2(b0.w, b1.w);
  }
  if (A_BF16){
    const unsigned* A = (const unsigned*)Aptr;
    #pragma unroll
    for (int i = 0; i < 8; ++i){
      int idx = t + i * 256;
      int row = idx >> 5, c2 = idx & 31;
      int grow = min(row0 + row, M - 1);
      uint2 v = *(const uint2*)&A[(size_t)grow * 64 + c2 * 2];
      Alds[row * 68 + c2 * 2]     = v.x;
      Alds[row * 68 + c2 * 2 + 1] = v.y;
    }
  } else {
    const float* A = (const float*)Aptr;
    #pragma unroll
    for (int i = 0; i < 8; ++i){
      int idx = t + i * 256;
      int row = idx >> 5, k4 = idx & 31;
      int grow = min(row0 + row, M - 1);
      float4 v = *(const float4*)&A[(size_t)grow * 128 + k4 * 4];
      Alds[row * 68 + k4 * 2]     = pack2(v.x, v.y);
      Alds[row * 68 + k4 * 2 + 1] = pack2(v.z, v.w);
    }
  }
  __syncthreads();

  const int wv = t >> 6, l = t & 63, quad = l >> 4, n16 = l & 15;
  f32x4 acc[8];
  #pragma unroll
  for (int nt = 0; nt < 8; ++nt) acc[nt] = (f32x4){0.f, 0.f, 0.f, 0.f};
  const int arow = wv * 16 + n16;
  #pragma unroll
  for (int ks = 0; ks < 4; ++ks){
    bf16x8 af = *(const bf16x8*)&Alds[arow * 68 + ks * 16 + quad * 4];
    #pragma unroll
    for (int nt = 0; nt < 8; ++nt){
      bf16x8 bfr = *(const bf16x8*)&Blds[(nt * 16 + n16) * 68 + ks * 16 + quad * 4];
      acc[nt] = __builtin_amdgcn_mfma_f32_16x16x32_bf16(af, bfr, acc[nt], 0, 0, 0);
    }
  }
  #pragma unroll
  for (int nt = 0; nt < 8; ++nt){
    #pragma unroll
    for (int r = 0; r < 4; ++r){
      int row = row0 + wv * 16 + quad * 4 + r;
      float sc = scale[min(row, M - 1)];
      float v = acc[nt][r] * sc;
      float vhi = __shfl_xor(v, 1);
      if (((l & 1) == 0) && row < M)
        Cmat[(size_t)row * 64 + nt * 8 + (n16 >> 1)] = pack2(v, vhi);
    }
  }
}

// ---------------------------------------------------------------------------
// CSR conv body (quarter-wave uint4 gather), as device fn
// ---------------------------------------------------------------------------
__device__ void conv_body(int wblk, const unsigned* __restrict__ Ts, const float* __restrict__ dis,
                          const int* __restrict__ rowptr, const int* __restrict__ esrc,
                          const float* __restrict__ bias, unsigned* __restrict__ Hout){
  int w = wblk * 4 + (threadIdx.x >> 6);
  int l = threadIdx.x & 63;
  int q = l & 15, h = l >> 4;
  int beg = rowptr[w], end = rowptr[w + 1];
  float acc[8] = {0.f,0.f,0.f,0.f,0.f,0.f,0.f,0.f};
  for (int base = beg; base < end; base += 64){
    int n = min(64, end - base);
    int eid = esrc[base + min(l, n - 1)];
    int j = 0;
    for (; j + 8 <= n; j += 8){
      int s0 = __shfl(eid, j + h);
      int s1 = __shfl(eid, j + 4 + h);
      uint4 u0 = *(const uint4*)&Ts[(size_t)s0 * 64 + q * 4];
      uint4 u1 = *(const uint4*)&Ts[(size_t)s1 * 64 + q * 4];
      acc[0] += bf16lo(u0.x); acc[1] += bf16hi(u0.x);
      acc[2] += bf16lo(u0.y); acc[3] += bf16hi(u0.y);
      acc[4] += bf16lo(u0.z); acc[5] += bf16hi(u0.z);
      acc[6] += bf16lo(u0.w); acc[7] += bf16hi(u0.w);
      acc[0] += bf16lo(u1.x); acc[1] += bf16hi(u1.x);
      acc[2] += bf16lo(u1.y); acc[3] += bf16hi(u1.y);
      acc[4] += bf16lo(u1.z); acc[5] += bf16hi(u1.z);
      acc[6] += bf16lo(u1.w); acc[7] += bf16hi(u1.w);
    }
    for (; j < n; j += 4){
      int ei = j + h;
      int s = __shfl(eid, min(ei, n - 1));
      uint4 u = *(const uint4*)&Ts[(size_t)s * 64 + q * 4];
      if (ei < n){
        acc[0] += bf16lo(u.x); acc[1] += bf16hi(u.x);
        acc[2] += bf16lo(u.y); acc[3] += bf16hi(u.y);
        acc[4] += bf16lo(u.z); acc[5] += bf16hi(u.z);
        acc[6] += bf16lo(u.w); acc[7] += bf16hi(u.w);
      }
    }
  }
  #pragma unroll
  for (int k = 0; k < 8; ++k){
    acc[k] += __shfl_xor(acc[k], 16);
    acc[k] += __shfl_xor(acc[k], 32);
  }
  float d = dis[w];
  uint4 us = *(const uint4*)&Ts[(size_t)w * 64 + q * 4];
  float4 b0 = *(const float4*)&bias[q * 8];
  float4 b1 = *(const float4*)&bias[q * 8 + 4];
  float r0 = fmaxf(fmaf(d, acc[0] + bf16lo(us.x), b0.x), 0.f);
  float r1 = fmaxf(fmaf(d, acc[1] + bf16hi(us.x), b0.y), 0.f);
  float r2 = fmaxf(fmaf(d, acc[2] + bf16lo(us.y), b0.z), 0.f);
  float r3 = fmaxf(fmaf(d, acc[3] + bf16hi(us.y), b0.w), 0.f);
  float r4 = fmaxf(fmaf(d, acc[4] + bf16lo(us.z), b1.x), 0.f);
  float r5 = fmaxf(fmaf(d, acc[5] + bf16hi(us.z), b1.y), 0.f);
  float r6 = fmaxf(fmaf(d, acc[6] + bf16lo(us.w), b1.z), 0.f);
  float r7 = fmaxf(fmaf(d, acc[7] + bf16hi(us.w), b1.w), 0.f);
  if (h == 0){
    uint4 o;
    o.x = pack2(r0, r1); o.y = pack2(r2, r3);
    o.z = pack2(r4, r5); o.w = pack2(r6, r7);
    *(uint4*)&Hout[(size_t)w * 64 + q * 4] = o;
  }
}

// psrc build body (device fn): one wave per cluster
__device__ void psrc_body(int cblk, const int* __restrict__ rowptrn, const int* __restrict__ nidx,
                          const int* __restrict__ rowptr1, const int* __restrict__ esrc1,
                          const int* __restrict__ cluster, const int* __restrict__ rowptr2,
                          int* __restrict__ psrcC){
  int c = cblk * 4 + (threadIdx.x >> 6);
  int l = threadIdx.x & 63;
  int mb = rowptrn[c], me = rowptrn[c + 1];
  int cnt = me - mb;
  int base_l = 0, d_l = 0;
  if (l < cnt){
    int v = nidx[mb + l];
    base_l = rowptr1[v];
    d_l = rowptr1[v + 1] - base_l;
  }
  int pref = d_l;
  #pragma unroll
  for (int off = 1; off < 64; off <<= 1){
    int u = __shfl_up(pref, off);
    if (l >= off) pref += u;
  }
  int total = __shfl(pref, 63);
  int wbase = rowptr2[c];
  int iters = (total + 63) >> 6;
  for (int k = 0; k < iters; ++k){
    int idx = k * 64 + l;
    int idxc = min(idx, total - 1);
    int m = 0;
    for (int j = 0; j < cnt; ++j){
      int pj = __shfl(pref, j);
      if (idxc >= pj) m = j + 1;
    }
    int pm = __shfl(pref, m);
    int dm = __shfl(d_l, m);
    int bm = __shfl(base_l, m);
    int e = bm + idxc - (pm - dm);
    int sc = cluster[esrc1[e]];
    if (idx < total) psrcC[wbase + idx] = sc;
  }
}

// ---------------------------------------------------------------------------
// node 7: gemm1 || fill_n (grid-partitioned)
// ---------------------------------------------------------------------------
__launch_bounds__(256)
__global__ void gemm1_filln(const float* __restrict__ x, const float* __restrict__ W1,
                            const float* __restrict__ dis1, unsigned* __restrict__ Ts1,
                            const int* __restrict__ cluster, int* __restrict__ curn,
                            int* __restrict__ nidx){
  if (blockIdx.x < G1){
    gemm_body<false>(blockIdx.x, x, W1, dis1, Ts1, N_NODES);
  } else {
    int v = (blockIdx.x - G1) * 256 + threadIdx.x;
    if (v < N_NODES) nidx[atomicAdd(&curn[cluster[v]], 1)] = v;
  }
}

// node 8: conv1 || psrc_build
__launch_bounds__(256)
__global__ void conv1_psrc(const unsigned* __restrict__ Ts1, const float* __restrict__ dis1,
                           const int* __restrict__ rowptr1, const int* __restrict__ esrc1,
                           const float* __restrict__ b1, unsigned* __restrict__ h1,
                           const int* __restrict__ rowptrn, const int* __restrict__ nidx,
                           const int* __restrict__ cluster, const int* __restrict__ rowptr2,
                           int* __restrict__ psrcC){
  if (blockIdx.x < C1)
    conv_body(blockIdx.x, Ts1, dis1, rowptr1, esrc1, b1, h1);
  else
    psrc_body(blockIdx.x - C1, rowptrn, nidx, rowptr1, esrc1, cluster, rowptr2, psrcC);
}

__device__ __forceinline__ void atomicMaxPosF(float* addr, float v){
  atomicMax((int*)addr, __float_as_int(v));
}

// node 9: cluster_gather (+cntp) || pre_pool (grid-partitioned)
__launch_bounds__(256)
__global__ void cluster_pre(const unsigned* __restrict__ h1, const int* __restrict__ rowptrn,
                            const int* __restrict__ nidx, const int* __restrict__ batch,
                            unsigned* __restrict__ hp, int* __restrict__ batchp,
                            int* __restrict__ cntp,
                            float* __restrict__ psum, float* __restrict__ pmax){
  if (blockIdx.x < CG){
    // ---- cluster mean pool + batch_p + cntp ----
    int c = blockIdx.x * 4 + (threadIdx.x >> 6);
    int l = threadIdx.x & 63;
    int q = l & 15, h = l >> 4;
    int mb = rowptrn[c], me = rowptrn[c + 1];
    float acc[8] = {0.f,0.f,0.f,0.f,0.f,0.f,0.f,0.f};
    int vmax = -1;
    for (int base = mb; base < me; base += 64){
      int n = min(64, me - base);
      int vid = nidx[base + min(l, n - 1)];
      if (l < n) vmax = max(vmax, vid);
      int j = 0;
      for (; j + 8 <= n; j += 8){
        int s0 = __shfl(vid, j + h);
        int s1 = __shfl(vid, j + 4 + h);
        uint4 u0 = *(const uint4*)&h1[(size_t)s0 * 64 + q * 4];
        uint4 u1 = *(const uint4*)&h1[(size_t)s1 * 64 + q * 4];
        acc[0] += bf16lo(u0.x); acc[1] += bf16hi(u0.x);
        acc[2] += bf16lo(u0.y); acc[3] += bf16hi(u0.y);
        acc[4] += bf16lo(u0.z); acc[5] += bf16hi(u0.z);
        acc[6] += bf16lo(u0.w); acc[7] += bf16hi(u0.w);
        acc[0] += bf16lo(u1.x); acc[1] += bf16hi(u1.x);
        acc[2] += bf16lo(u1.y); acc[3] += bf16hi(u1.y);
        acc[4] += bf16lo(u1.z); acc[5] += bf16hi(u1.z);
        acc[6] += bf16lo(u1.w); acc[7] += bf16hi(u1.w);
      }
      for (; j < n; j += 4){
        int ei = j + h;
        int s = __shfl(vid, min(ei, n - 1));
        uint4 u = *(const uint4*)&h1[(size_t)s * 64 + q * 4];
        if (ei < n){
          acc[0] += bf16lo(u.x); acc[1] += bf16hi(u.x);
          acc[2] += bf16lo(u.y); acc[3] += bf16hi(u.y);
          acc[4] += bf16lo(u.z); acc[5] += bf16hi(u.z);
          acc[6] += bf16lo(u.w); acc[7] += bf16hi(u.w);
        }
      }
    }
    #pragma unroll
    for (int k = 0; k < 8; ++k){
      acc[k] += __shfl_xor(acc[k], 16);
      acc[k] += __shfl_xor(acc[k], 32);
    }
    #pragma unroll
    for (int off = 32; off > 0; off >>= 1) vmax = max(vmax, __shfl_xor(vmax, off));
    float inv = 1.0f / (float)max(me - mb, 1);
    if (h == 0){
      uint4 o;
      o.x = pack2(acc[0] * inv, acc[1] * inv);
      o.y = pack2(acc[2] * inv, acc[3] * inv);
      o.z = pack2(acc[4] * inv, acc[5] * inv);
      o.w = pack2(acc[6] * inv, acc[7] * inv);
      *(uint4*)&hp[(size_t)c * 64 + q * 4] = o;
    }
    if (l == 0){
      int bp = (vmax >= 0) ? batch[vmax] : 0;  // batch sorted by node id
      batchp[c] = bp;
      atomicAdd(&cntp[bp], 1);
    }
  } else {
    // ---- pre-pool over contiguous sorted-batch range ----
    int bid = blockIdx.x - CG;
    int g = bid / PRE_SPLIT, sp = bid % PRE_SPLIT;
    int t = threadIdx.x, w = t >> 6, l = t & 63;
    int s0 = bsearch_batch(batch, g), s1 = bsearch_batch(batch, g + 1);
    int n = s1 - s0;
    int per = (n + PRE_SPLIT - 1) / PRE_SPLIT;
    int b0 = s0 + sp * per, b1 = min(b0 + per, s1);
    float2 a0{0.f,0.f}, a1{0.f,0.f}, a2{0.f,0.f}, a3{0.f,0.f};
    float2 mx{0.f,0.f};
    int i = b0 + w;
    for (; i + 12 < b1; i += 16){
      unsigned u0 = h1[(size_t)(i     ) * 64 + l];
      unsigned u1 = h1[(size_t)(i +  4) * 64 + l];
      unsigned u2 = h1[(size_t)(i +  8) * 64 + l];
      unsigned u3 = h1[(size_t)(i + 12) * 64 + l];
      float f0x = bf16lo(u0), f0y = bf16hi(u0);
      float f1x = bf16lo(u1), f1y = bf16hi(u1);
      float f2x = bf16lo(u2), f2y = bf16hi(u2);
      float f3x = bf16lo(u3), f3y = bf16hi(u3);
      a0.x += f0x; a0.y += f0y; a1.x += f1x; a1.y += f1y;
      a2.x += f2x; a2.y += f2y; a3.x += f3x; a3.y += f3y;
      mx.x = fmaxf(fmaxf(mx.x, fmaxf(f0x, f1x)), fmaxf(f2x, f3x));
      mx.y = fmaxf(fmaxf(mx.y, fmaxf(f0y, f1y)), fmaxf(f2y, f3y));
    }
    for (; i < b1; i += 4){
      unsigned u = h1[(size_t)i * 64 + l];
      float fx = bf16lo(u), fy = bf16hi(u);
      a0.x += fx; a0.y += fy;
      mx.x = fmaxf(mx.x, fx); mx.y = fmaxf(mx.y, fy);
    }
    __shared__ float2 ssum[4][64], smax[4][64];
    ssum[w][l] = { a0.x + a1.x + a2.x + a3.x, a0.y + a1.y + a2.y + a3.y };
    smax[w][l] = mx;
    __syncthreads();
    if (w == 0){
      float2 S = ssum[0][l], M = smax[0][l];
      #pragma unroll
      for (int k = 1; k < 4; ++k){
        S.x += ssum[k][l].x; S.y += ssum[k][l].y;
        M.x = fmaxf(M.x, smax[k][l].x); M.y = fmaxf(M.y, smax[k][l].y);
      }
      atomicAdd(&psum[g * 128 + 2 * l], S.x);
      atomicAdd(&psum[g * 128 + 2 * l + 1], S.y);
      atomicMaxPosF(&pmax[g * 128 + 2 * l], M.x);
      atomicMaxPosF(&pmax[g * 128 + 2 * l + 1], M.y);
    }
  }
}

// node 10: gemm2 || cluster->graph CSR (single extra block)
__launch_bounds__(256)
__global__ void gemm2_ccsr(const unsigned* __restrict__ hp, const float* __restrict__ W2,
                           const float* __restrict__ dis2, unsigned* __restrict__ Ts2,
                           const int* __restrict__ cntp, const int* __restrict__ batchp,
                           int* __restrict__ gbasep, int* __restrict__ cidx){
  if (blockIdx.x < G2){
    gemm_body<true>(blockIdx.x, hp, W2, dis2, Ts2, N_CLUST);
  } else {
    __shared__ int curL[64];
    int t = threadIdx.x;
    if (t < 64){
      int v = cntp[t];
      int s = v;
      #pragma unroll
      for (int off = 1; off < 64; off <<= 1){
        int u = __shfl_up(s, off);
        if (t >= off) s += u;
      }
      curL[t] = s - v;
      gbasep[t] = s - v;
      if (t == 63) gbasep[64] = s;
    }
    __syncthreads();
    for (int c0 = 0; c0 < N_CLUST; c0 += 256){
      int c = c0 + t;
      if (c < N_CLUST){
        int r = atomicAdd(&curL[batchp[c]], 1);
        cidx[r] = c;
      }
    }
  }
}

// nodes 11-13: standalone conv / gemm wrappers
__launch_bounds__(256)
__global__ void conv_k(const unsigned* __restrict__ Ts, const float* __restrict__ dis,
                       const int* __restrict__ rowptr, const int* __restrict__ esrc,
                       const float* __restrict__ bias, unsigned* __restrict__ Hout){
  conv_body(blockIdx.x, Ts, dis, rowptr, esrc, bias, Hout);
}

__launch_bounds__(256)
__global__ void gemm_k(const unsigned* __restrict__ A, const float* __restrict__ B,
                       const float* __restrict__ scale, unsigned* __restrict__ Cmat, int M){
  gemm_body<true>(blockIdx.x, A, B, scale, Cmat, M);
}

// node 14: post-pool gather via graph->cluster CSR
__launch_bounds__(256)
__global__ void post_pool_g(const unsigned* __restrict__ hp3, const int* __restrict__ gbasep,
                            const int* __restrict__ cidx,
                            float* __restrict__ psum, float* __restrict__ pmax){
  int g = blockIdx.x / POST_SPLIT, sp = blockIdx.x % POST_SPLIT;
  int t = threadIdx.x, w = t >> 6, l = t & 63;
  int s0 = gbasep[g], s1 = gbasep[g + 1];
  int n = s1 - s0;
  int per = (n + POST_SPLIT * 4 - 1) / (POST_SPLIT * 4);
  int b0 = s0 + (sp * 4 + w) * per, b1 = min(b0 + per, s1);
  float2 a0{0.f,0.f}, a1{0.f,0.f}, a2{0.f,0.f}, a3{0.f,0.f};
  float2 mx{0.f,0.f};
  for (int base = b0; base < b1; base += 64){
    int nn = min(64, b1 - base);
    int cid = cidx[base + min(l, nn - 1)];
    int j = 0;
    for (; j + 4 <= nn; j += 4){
      int c0 = __shfl(cid, j);
      int c1 = __shfl(cid, j + 1);
      int c2 = __shfl(cid, j + 2);
      int c3 = __shfl(cid, j + 3);
      unsigned u0 = hp3[(size_t)c0 * 64 + l];
      unsigned u1 = hp3[(size_t)c1 * 64 + l];
      unsigned u2 = hp3[(size_t)c2 * 64 + l];
      unsigned u3 = hp3[(size_t)c3 * 64 + l];
      float f0x = bf16lo(u0), f0y = bf16hi(u0);
      float f1x = bf16lo(u1), f1y = bf16hi(u1);
      float f2x = bf16lo(u2), f2y = bf16hi(u2);
      float f3x = bf16lo(u3), f3y = bf16hi(u3);
      a0.x += f0x; a0.y += f0y; a1.x += f1x; a1.y += f1y;
      a2.x += f2x; a2.y += f2y; a3.x += f3x; a3.y += f3y;
      mx.x = fmaxf(fmaxf(mx.x, fmaxf(f0x, f1x)), fmaxf(f2x, f3x));
      mx.y = fmaxf(fmaxf(mx.y, fmaxf(f0y, f1y)), fmaxf(f2y, f3y));
    }
    for (; j < nn; ++j){
      int c = __shfl(cid, j);
      unsigned u = hp3[(size_t)c * 64 + l];
      float fx = bf16lo(u), fy = bf16hi(u);
      a0.x += fx; a0.y += fy;
      mx.x = fmaxf(mx.x, fx); mx.y = fmaxf(mx.y, fy);
    }
  }
  __shared__ float2 ssum[4][64], smax[4][64];
  ssum[w][l] = { a0.x + a1.x + a2.x + a3.x, a0.y + a1.y + a2.y + a3.y };
  smax[w][l] = mx;
  __syncthreads();
  if (w == 0){
    float2 S = ssum[0][l], M = smax[0][l];
    #pragma unroll
    for (int k = 1; k < 4; ++k){
      S.x += ssum[k][l].x; S.y += ssum[k][l].y;
      M.x = fmaxf(M.x, smax[k][l].x); M.y = fmaxf(M.y, smax[k][l].y);
    }
    atomicAdd(&psum[g * 128 + 2 * l], S.x);
    atomicAdd(&psum[g * 128 + 2 * l + 1], S.y);
    atomicMaxPosF(&pmax[g * 128 + 2 * l], M.x);
    atomicMaxPosF(&pmax[g * 128 + 2 * l + 1], M.y);
  }
}

// node 15: head (graph bounds inlined)
__launch_bounds__(128)
__global__ void head_kernel(const float* __restrict__ psum, const float* __restrict__ pmax,
                            const float* __restrict__ postsum, const float* __restrict__ postmax,
                            const int* __restrict__ batch, const int* __restrict__ cntp,
                            const float* __restrict__ l1w, const float* __restrict__ l1b,
                            const float* __restrict__ l2w, const float* __restrict__ l2b,
                            float* __restrict__ out){
  int g = blockIdx.x, t = threadIdx.x;
  __shared__ float z[512];
  __shared__ float a[128];
  __shared__ float logits[16];
  __shared__ float lse_s;
  int gs0 = bsearch_batch(batch, g), gs1 = bsearch_batch(batch, g + 1);
  float cpre  = (float)max(gs1 - gs0, 1);
  float cpost = fmaxf((float)cntp[g], 1.0f);
  z[t]       = psum[g * 128 + t] / cpre;
  z[128 + t] = pmax[g * 128 + t];
  z[256 + t] = postsum[g * 128 + t] / cpost;
  z[384 + t] = postmax[g * 128 + t];
  __syncthreads();
  float acc = l1b[t];
  #pragma unroll 8
  for (int k = 0; k < 512; ++k) acc = fmaf(z[k], l1w[k * 128 + t], acc);
  a[t] = fmaxf(acc, 0.f);
  __syncthreads();
  if (t < NCLSN){
    float s2 = l2b[t];
    for (int k = 0; k < 128; ++k) s2 = fmaf(a[k], l2w[k * NCLSN + t], s2);
    logits[t] = s2;
  }
  __syncthreads();
  if (t == 0){
    float m = logits[0];
    for (int c = 1; c < NCLSN; ++c) m = fmaxf(m, logits[c]);
    float s = 0.f;
    for (int c = 0; c < NCLSN; ++c) s += expf(logits[c] - m);
    lse_s = m + logf(s);
  }
  __syncthreads();
  if (t < NCLSN) out[g * NCLSN + t] = logits[t] - lse_s;
}

// ---------------------------------------------------------------------------
extern "C" void kernel_launch(void* const* d_in, const int* in_sizes, int n_in,
                              void* d_out, int out_size, void* d_ws, size_t ws_size,
                              hipStream_t stream){
  const float* x       = (const float*)d_in[0];
  const int*   ei      = (const int*)  d_in[1];
  const int*   batch   = (const int*)  d_in[2];
  const int*   cluster = (const int*)  d_in[3];
  const float* W1      = (const float*)d_in[6];
  const float* b1      = (const float*)d_in[7];
  const float* W2      = (const float*)d_in[8];
  const float* b2      = (const float*)d_in[9];
  const float* W3      = (const float*)d_in[10];
  const float* b3      = (const float*)d_in[11];
  const float* l1w     = (const float*)d_in[12];
  const float* l1b     = (const float*)d_in[13];
  const float* l2w     = (const float*)d_in[14];
  const float* l2b     = (const float*)d_in[15];
  float* out = (float*)d_out;

  char* base = (char*)d_ws;
  size_t off = 0;
  auto alloc = [&](size_t bytes) -> char* {
    char* p = base + off;
    off += (bytes + 255) & ~size_t(255);
    return p;
  };
  // ---- zero zone (cleared by count_kernel's zero blocks) ----
  char*  zbase  = base + off;
  int*   cntn   = (int*)  alloc((size_t)N_CLUST * 4);
  int*   deg2   = (int*)  alloc((size_t)N_CLUST * 4);
  int*   cntp   = (int*)  alloc((size_t)N_GRAPH * 4);
  float* pre_s  = (float*)alloc((size_t)N_GRAPH * 128 * 4);
  float* pre_m  = (float*)alloc((size_t)N_GRAPH * 128 * 4);
  float* post_s = (float*)alloc((size_t)N_GRAPH * 128 * 4);
  float* post_m = (float*)alloc((size_t)N_GRAPH * 128 * 4);
  size_t zsize = off;
  // ---- plain buffers (bf16 feature rows: 64 uints per row) ----
  unsigned* Ts1   = (unsigned*)alloc((size_t)N_NODES * 64 * 4);  // later aliased
  unsigned* h1    = (unsigned*)alloc((size_t)N_NODES * 64 * 4);  // stage buf aliases here
  int*   esrc1   = (int*)  alloc((size_t)N_EDGES * 4);
  int*   psrcC   = (int*)  alloc((size_t)N_EDGES * 4);
  int*   deg1    = (int*)  alloc((size_t)N_NODES * 4);
  int*   rowptr1 = (int*)  alloc((size_t)(N_NODES + 1) * 4);
  int*   rowptrn = (int*)  alloc((size_t)(N_CLUST + 1) * 4);
  int*   curn    = (int*)  alloc((size_t)N_CLUST * 4);
  int*   rowptr2 = (int*)  alloc((size_t)(N_CLUST + 1) * 4);
  int*   nidx    = (int*)  alloc((size_t)N_NODES * 4);
  float* dis1    = (float*)alloc((size_t)N_NODES * 4);
  float* dis2    = (float*)alloc((size_t)N_CLUST * 4);
  int*   batchp  = (int*)  alloc((size_t)N_CLUST * 4);
  int*   bsum    = (int*)  alloc((size_t)NBT * 4);
  int*   gcnt1   = (int*)  alloc((size_t)NBKT1 * 4);
  int*   bhist   = (int*)  alloc((size_t)NEB * NBKT1 * 4);
  int*   boffs   = (int*)  alloc((size_t)NEB * NBKT1 * 4);
  int*   gbasep  = (int*)  alloc((size_t)(N_GRAPH + 1) * 4);
  int*   cidx    = (int*)  alloc((size_t)N_CLUST * 4);
  // stage buffer aliases the (not-yet-written) h1 region (6.4 MB <= 25.6 MB)
  unsigned int* stage1 = (unsigned int*)h1;
  // aliases into Ts1 (dead after conv1): 4 x 25000*64 uints = exactly Ts1 size
  unsigned* hp  = Ts1;
  unsigned* Ts2 = Ts1 + (size_t)N_CLUST * 64;
  unsigned* hp2 = Ts1 + (size_t)2 * N_CLUST * 64;
  unsigned* hp3 = Ts1 + (size_t)3 * N_CLUST * 64;
  unsigned* Ts3 = Ts2;

  (void)in_sizes; (void)n_in; (void)out_size; (void)ws_size;

  int zwords4 = (int)(zsize / 16);

  // 1: histograms + workspace zeroing
  count_kernel<<<NEB + NZB, 1024, 0, stream>>>(ei, bhist, (uint4*)zbase, zwords4);
  // 2: column scan
  colscan<<<NBKT1, 512, 0, stream>>>(bhist, boffs, gcnt1);
  // 3: scatter (in-block bucket bases)
  scatter_kernel<<<NEB, 1024, 0, stream>>>(ei, gcnt1, boffs, stage1);
  // 4: bucket sort + deg1 + node_prep
  bucket_sort<<<NBKT1, 1024, 0, stream>>>(stage1, gcnt1, esrc1, deg1, cluster, cntn, deg2);
  // 5: per-block sums for the 3-segment scan
  block_sums<<<NBT, 256, 0, stream>>>(deg1, cntn, deg2, bsum);
  // 6: final scan (in-block bsum scan), rowptrs + dis
  scan_final<<<NBT, 256, 0, stream>>>(deg1, cntn, deg2, bsum,
                                      rowptr1, dis1, rowptrn, curn, rowptr2, dis2);
  // 7: gemm1 || fill_n
  gemm1_filln<<<G1 + FN, 256, 0, stream>>>(x, W1, dis1, Ts1, cluster, curn, nidx);
  // 8: conv1 || psrc_build
  conv1_psrc<<<C1 + PS, 256, 0, stream>>>(Ts1, dis1, rowptr1, esrc1, b1, h1,
                                          rowptrn, nidx, cluster, rowptr2, psrcC);
  // 9: cluster_gather (+cntp) || pre_pool
  cluster_pre<<<CG + PP, 256, 0, stream>>>(h1, rowptrn, nidx, batch, hp, batchp, cntp,
                                           pre_s, pre_m);
  // 10: gemm2 || graph->cluster CSR
  gemm2_ccsr<<<G2 + 1, 256, 0, stream>>>(hp, W2, dis2, Ts2, cntp, batchp, gbasep, cidx);
  // 11: conv2
  conv_k<<<N_CLUST / 4, 256, 0, stream>>>(Ts2, dis2, rowptr2, psrcC, b2, hp2);
  // 12: gemm3
  gemm_k<<<G2, 256, 0, stream>>>(hp2, W3, dis2, Ts3, N_CLUST);
  // 13: conv3
  conv_k<<<N_CLUST / 4, 256, 0, stream>>>(Ts3, dis2, rowptr2, psrcC, b3, hp3);
  // 14: post pools
  post_pool_g<<<N_GRAPH * POST_SPLIT, 256, 0, stream>>>(hp3, gbasep, cidx, post_s, post_m);
  // 15: head
  head_kernel<<<N_GRAPH, 128, 0, stream>>>(pre_s, pre_m, post_s, post_m, batch, cntp,
                                           l1w, l1b, l2w, l2b, out);
}